// Round 15
// baseline (186.590 us; speedup 1.0000x reference)
//
#include <hip/hip_runtime.h>
#include <hip/hip_runtime_api.h>
#include <math.h>

#define NBATCH 2
#define QQ     131072
#define HH     64
#define WWID   2048
#define CC     64
#define HWSZ   (HH*WWID)   /* 131072 = 2^17 */

constexpr int ROWS    = 64;    // rows per block
constexpr int THREADS = 256;   // 4 waves; wave tile = 64 rows x N/4 cols

// A: 64 rows x 512 B (256 bf16), XOR-swizzled; byte ^= (row&7)<<4
constexpr int ASTR_B = 512;

// dynamic-LDS byte offsets
constexpr int OFF_A   = 0;                 // 32768 B
constexpr int OFF_TAP = 32768;             // tap[64][4] int  = 1024 B
constexpr int OFF_PXY = OFF_TAP + 1024;    // pxy[64][4] f32  = 1024 B
constexpr int OFF_E3  = OFF_PXY + 1024;    // ew3 64x4 f32    = 1024 B
constexpr int LDS_BYTES = OFF_E3 + 1024;   // 35840 B

// packed fragment-layout weight offsets in elements (Kp = K padded to 64)
constexpr int WOFF_PE0 = 0;       // N=64,  Kp=64   -> 4096
constexpr int WOFF_PE1 = 4096;    // N=128, Kp=64   -> 8192
constexpr int WOFF_PE2 = 12288;   // N=256, Kp=128  -> 32768
constexpr int WOFF_E0  = 45056;   // N=256, Kp=256  -> 65536
constexpr int WOFF_E1  = 110592;  // N=128, Kp=256  -> 32768
constexpr int WOFF_E2  = 143360;  // N=64,  Kp=128  -> 8192
constexpr int WTOTAL   = 151552;

typedef __attribute__((ext_vector_type(8))) short bf16x8;
typedef __attribute__((ext_vector_type(4))) float f32x4;

__device__ __forceinline__ ushort f2bf(float f) {
    union { float f; unsigned u; } x; x.f = f;
    unsigned r = x.u + 0x7fffu + ((x.u >> 16) & 1u);   // RNE
    return (ushort)(r >> 16);
}
__device__ __forceinline__ float bf2f(ushort h) {
    union { unsigned u; float f; } x; x.u = ((unsigned)h) << 16;
    return x.f;
}
// pack 2 f32 -> 2 bf16 in one u32 (RNE, gfx950). lo = cvt(a), hi = cvt(b).
__device__ __forceinline__ unsigned cvtpk(float a, float b) {
    unsigned r;
    asm("v_cvt_pk_bf16_f32 %0, %1, %2" : "=v"(r) : "v"(a), "v"(b));
    return r;
}

// swizzled A byte address (XOR flips bits 4-6 by row)
__device__ __forceinline__ int swA(int row, int colByte) {
    return row * ASTR_B + (colByte ^ ((row & 7) << 4));
}

// ---------------------------------------------------------------------------
// Weight prep: fp32 [K][N] -> bf16 MFMA-fragment-packed [chunks][tiles][512]
// tile = 16 cols x 32 k, lane-ordered: elem(lane,j) = W[k0+(lane>>4)*8+j][n0+(lane&15)]
// chunk = 64 k-wide: tiles ordered (n>>4)*2 + kk
// ---------------------------------------------------------------------------
struct WDesc { const float* src; int K; int N; int kshift; };  // Kp = 1<<kshift
struct WPack { WDesc d[6]; };

__global__ __launch_bounds__(256) void prep_weights(WPack p, ushort* __restrict__ dst)
{
    int e = blockIdx.x * 256 + threadIdx.x;
    int off = 0;
    #pragma unroll
    for (int L = 0; L < 6; ++L) {
        const int Kp = 1 << p.d[L].kshift;
        const int N  = p.d[L].N;
        const int sz = N * Kp;
        if (e < sz) {
            const int n = e / Kp;
            const int k = e & (Kp - 1);
            const float v = (k < p.d[L].K) ? p.d[L].src[(size_t)k * N + n] : 0.f;
            const int chunk = k >> 6;
            const int kk    = (k >> 5) & 1;
            const int tile  = chunk * ((N >> 4) * 2) + (n >> 4) * 2 + kk;
            const int lane  = (n & 15) + (((k >> 3) & 3) << 4);
            const int j     = k & 7;
            dst[off + tile * 512 + lane * 8 + j] = f2bf(v);
            return;
        }
        e -= sz; off += sz;
    }
}

// ---------------------------------------------------------------------------
// Feat prep: NCHW f32 -> NHWC bf16, plus xy = sqrt(d1^2+d2^2)
// ---------------------------------------------------------------------------
__global__ __launch_bounds__(256) void prep_feat(
    const float* __restrict__ depth, const float* __restrict__ feat,
    ushort* __restrict__ nhwc, float* __restrict__ xy)
{
    const int idx = blockIdx.x * 256 + threadIdx.x;
    const int b   = idx >> 17;
    const int yx  = idx & (HWSZ - 1);

    const float d1 = depth[(b * 3 + 1) * HWSZ + yx];
    const float d2 = depth[(b * 3 + 2) * HWSZ + yx];
    xy[idx] = sqrtf(d1 * d1 + d2 * d2);

    const float* fp = feat + (size_t)b * CC * HWSZ + yx;
    ushort* op = nhwc + (size_t)idx * CC;
    #pragma unroll
    for (int c = 0; c < CC; c += 8) {
        union { uint4 v; ushort u[8]; } t;
        #pragma unroll
        for (int j = 0; j < 8; ++j) t.u[j] = f2bf(fp[(size_t)(c + j) * HWSZ]);
        *(uint4*)(op + c) = t.v;
    }
}

// ---------------------------------------------------------------------------
// One dense layer, in place on A (bf16, swizzled LDS). 4 waves split N.
// Wave tile 64 rows x N/4 cols: each B-fragment load feeds FOUR MFMAs.
// SWAPPED operands: mfma(w_frag, a_frag) -> lane holds 4 consecutive output
// cols of one row -> packed ds_write_b64 writeback.
// FEAT_ADD (N==256 only): fuse the q_feat gather-add into the writeback —
// wave wv's columns [wv*64, wv*64+64) are exactly tap slot s=wv's channels,
// and the fp32 accumulators are still in registers, so add bf16 feat here
// instead of a separate LDS read-modify-write pass (+barrier) later.
// ---------------------------------------------------------------------------
template <int K, int N, bool RELU, bool FEAT_ADD = false>
__device__ __forceinline__ void dense_layer(
    char* __restrict__ sA, const ushort* __restrict__ Wt,
    const float* __restrict__ Bg, int tid,
    const ushort* __restrict__ nhwc_bt = nullptr,
    const int* __restrict__ sTap = nullptr)
{
    constexpr int TN  = N / 64;        // 16-col tiles per wave
    constexpr int NCH = K / 64;        // 64-wide K chunks

    const int lane = tid & 63, wv = tid >> 6;   // wv in 0..3
    const int col0 = wv * (N / 4);
    const int lrow = lane & 15;
    const int lkb  = (lane >> 4) * 16;   // byte offset of this lane's 8 bf16 in k

    f32x4 acc[4][TN];
    #pragma unroll
    for (int tm = 0; tm < 4; ++tm)
        #pragma unroll
        for (int tn = 0; tn < TN; ++tn) acc[tm][tn] = (f32x4){0.f, 0.f, 0.f, 0.f};

    const char* wbase = (const char*)Wt + (size_t)lane * 16;

    #pragma unroll
    for (int c = 0; c < NCH; ++c) {
        #pragma unroll
        for (int ks = 0; ks < 64; ks += 32) {
            const int cb = (c * 64 + ks) * 2 + lkb;
            const bf16x8 a0 = *(const bf16x8*)(sA + swA(     lrow, cb));
            const bf16x8 a1 = *(const bf16x8*)(sA + swA(16 + lrow, cb));
            const bf16x8 a2 = *(const bf16x8*)(sA + swA(32 + lrow, cb));
            const bf16x8 a3 = *(const bf16x8*)(sA + swA(48 + lrow, cb));
            #pragma unroll
            for (int tn = 0; tn < TN; ++tn) {
                const int tile = c * ((N >> 4) * 2) + ((col0 >> 4) + tn) * 2 + (ks >> 5);
                const bf16x8 bw = *(const bf16x8*)(wbase + tile * 1024);
                acc[0][tn] = __builtin_amdgcn_mfma_f32_16x16x32_bf16(bw, a0, acc[0][tn], 0, 0, 0);
                acc[1][tn] = __builtin_amdgcn_mfma_f32_16x16x32_bf16(bw, a1, acc[1][tn], 0, 0, 0);
                acc[2][tn] = __builtin_amdgcn_mfma_f32_16x16x32_bf16(bw, a2, acc[2][tn], 0, 0, 0);
                acc[3][tn] = __builtin_amdgcn_mfma_f32_16x16x32_bf16(bw, a3, acc[3][tn], 0, 0, 0);
            }
        }
    }
    __syncthreads();   // all waves done reading A -> safe in-place writeback

    // writeback: lane holds row = tm*16+lrow, cols = colb..colb+3
    #pragma unroll
    for (int tn = 0; tn < TN; ++tn) {
        const int colb = col0 + tn * 16 + (lane >> 4) * 4;
        const float4 b4 = *(const float4*)(Bg + colb);
        #pragma unroll
        for (int tm = 0; tm < 4; ++tm) {
            const int row = tm * 16 + lrow;
            float v0 = acc[tm][tn][0] + b4.x;
            float v1 = acc[tm][tn][1] + b4.y;
            float v2 = acc[tm][tn][2] + b4.z;
            float v3 = acc[tm][tn][3] + b4.w;
            if (FEAT_ADD) {
                const int s   = colb >> 6;           // tap slot (== wv for N=256)
                const int ch  = colb & 63;           // channel within tap
                const int tap = sTap[row * 4 + s];
                union { uint2 u2; ushort u[4]; } fv;
                fv.u2 = *(const uint2*)(nhwc_bt + (size_t)tap * CC + ch);
                v0 += bf2f(fv.u[0]); v1 += bf2f(fv.u[1]);
                v2 += bf2f(fv.u[2]); v3 += bf2f(fv.u[3]);
            }
            if (RELU) {
                v0 = fmaxf(v0, 0.f); v1 = fmaxf(v1, 0.f);
                v2 = fmaxf(v2, 0.f); v3 = fmaxf(v3, 0.f);
            }
            uint2 pk;
            pk.x = cvtpk(v0, v1);
            pk.y = cvtpk(v2, v3);
            *(uint2*)(sA + swA(row, colb * 2)) = pk;
        }
    }
    __syncthreads();
}

// ---------------------------------------------------------------------------
// Fused: taps + PE MLP (+fused gather) + encoder MLP + softmax + output
// __launch_bounds__(256, 3): 168-reg unified budget (acc[4][4]=64 + ~84 arch).
// ---------------------------------------------------------------------------
template <bool USE_WS>
__global__ __launch_bounds__(256, 3) void fused_kernel(
    const float* __restrict__ depth, const float* __restrict__ feat,
    const float* __restrict__ coord,
    const float* __restrict__ pb0, const float* __restrict__ pb1,
    const float* __restrict__ pb2,
    const float* __restrict__ eb0, const float* __restrict__ eb1,
    const float* __restrict__ eb2,
    const float* __restrict__ ew3, const float* __restrict__ eb3,
    const ushort* __restrict__ wt,
    const ushort* __restrict__ nhwc, const float* __restrict__ xyws,
    float* __restrict__ out)
{
    extern __shared__ char lds[];
    char*  sA   = lds + OFF_A;
    int*   sTap = (int*)(lds + OFF_TAP);
    float* sPxy = (float*)(lds + OFF_PXY);
    float* sE3  = (float*)(lds + OFF_E3);

    const int tid  = threadIdx.x;
    const int row0g = blockIdx.x * ROWS;
    const int b     = row0g >> 17;   // QQ = 2^17, ROWS | QQ
    const ushort* nhwc_bt = nhwc + (size_t)b * HWSZ * CC;

    // stage final-layer weights (64x4 f32)
    sE3[tid] = ew3[tid];

    // zero A cols 0..63 (pe0 K padded 8->64); swizzle permutes within bytes 0..127
    {
        const int r = tid >> 2, q = tid & 3;
        uint4 z; z.x = z.y = z.z = z.w = 0u;
        *(uint4*)(sA + r * ASTR_B + q * 32)      = z;
        *(uint4*)(sA + r * ASTR_B + q * 32 + 16) = z;
    }
    __syncthreads();

    // taps + rel coords + pred_xy; fp32, contraction OFF (match numpy rounding)
    {
        #pragma clang fp contract(off)
        const int r = tid >> 2, s = tid & 3;
        const int row = row0g + r;
        const float cy = coord[row * 2 + 0];
        const float cx = coord[row * 2 + 1];
        const float offy = (s < 2) ? -1.f : 1.f;
        const float offx = (s & 1) ? 1.f : -1.f;
        const float rx = 1.f / (float)HH, ry = 1.f / (float)WWID;
        float ccy = cy + (offy * rx + 1e-6f);
        float ccx = cx + (offx * ry + 1e-6f);
        ccy = fminf(fmaxf(ccy, -1.f + 1e-6f), 1.f - 1e-6f);
        ccx = fminf(fmaxf(ccx, -1.f + 1e-6f), 1.f - 1e-6f);
        int iy = (int)rintf(((ccy + 1.f) * (float)HH - 1.f) * 0.5f);
        int ix = (int)rintf(((ccx + 1.f) * (float)WWID - 1.f) * 0.5f);
        iy = min(max(iy, 0), HH - 1);
        ix = min(max(ix, 0), WWID - 1);
        const float qcy = -1.f + (2.f * (float)iy + 1.f) / (float)HH;
        const float qcx = -1.f + (2.f * (float)ix + 1.f) / (float)WWID;
        *(ushort*)(sA + swA(r, s * 4 + 0)) = f2bf((cy - qcy) * (float)HH);
        *(ushort*)(sA + swA(r, s * 4 + 2)) = f2bf((cx - qcx) * (float)WWID);
        const int tap = iy * WWID + ix;
        sTap[r * 4 + s] = tap;
        float px;
        if (USE_WS) {
            px = xyws[b * HWSZ + tap];
        } else {
            const float d1 = depth[(b * 3 + 1) * HWSZ + tap];
            const float d2 = depth[(b * 3 + 2) * HWSZ + tap];
            px = sqrtf(d1 * d1 + d2 * d2);
        }
        sPxy[r * 4 + s] = px;
    }
    __syncthreads();

    // PE MLP (rel coords in A cols 0..7, zero-padded to 64)
    dense_layer<64,  64,  true >(sA, wt + WOFF_PE0, pb0, tid);
    dense_layer<64,  128, true >(sA, wt + WOFF_PE1, pb1, tid);

    if (USE_WS) {
        // pe2 with the q_feat gather-add FUSED into its writeback
        dense_layer<128, 256, false, true>(sA, wt + WOFF_PE2, pb2, tid, nhwc_bt, sTap);
    } else {
        dense_layer<128, 256, false>(sA, wt + WOFF_PE2, pb2, tid);
        // separate gather-add (NCHW fallback)
        {
            const int gr = tid >> 2, gs = tid & 3;
            const int tap = sTap[gr * 4 + gs];
            const int cb0 = gs * 128;
            const float* fp = feat + (size_t)b * CC * HWSZ + tap;
            #pragma unroll 8
            for (int c = 0; c < CC; ++c) {
                ushort* p = (ushort*)(sA + swA(gr, cb0 + c * 2));
                *p = f2bf(bf2f(*p) + fp[(size_t)c * HWSZ]);
            }
        }
        __syncthreads();
    }

    // encoder MLP
    dense_layer<256, 256, true>(sA, wt + WOFF_E0, eb0, tid);
    dense_layer<256, 128, true>(sA, wt + WOFF_E1, eb1, tid);
    dense_layer<128, 64,  true>(sA, wt + WOFF_E2, eb2, tid);

    // final 64->4, softmax, weighted sum with pred_xy (4 threads per row)
    {
        const int fr = tid >> 2, sub = tid & 3;
        float l0 = 0.f, l1 = 0.f, l2 = 0.f, l3 = 0.f;
        #pragma unroll
        for (int kk = 0; kk < 16; ++kk) {
            const int k = sub * 16 + kk;
            const float a = bf2f(*(const ushort*)(sA + swA(fr, k * 2)));
            const float4 w = ((const float4*)sE3)[k];
            l0 = fmaf(a, w.x, l0);
            l1 = fmaf(a, w.y, l1);
            l2 = fmaf(a, w.z, l2);
            l3 = fmaf(a, w.w, l3);
        }
        #pragma unroll
        for (int m = 1; m <= 2; m <<= 1) {
            l0 += __shfl_xor(l0, m);
            l1 += __shfl_xor(l1, m);
            l2 += __shfl_xor(l2, m);
            l3 += __shfl_xor(l3, m);
        }
        if (sub == 0) {
            l0 += eb3[0]; l1 += eb3[1]; l2 += eb3[2]; l3 += eb3[3];
            const float m  = fmaxf(fmaxf(l0, l1), fmaxf(l2, l3));
            const float e0 = expf(l0 - m), e1 = expf(l1 - m);
            const float e2 = expf(l2 - m), e3 = expf(l3 - m);
            const float inv = 1.f / (e0 + e1 + e2 + e3);
            const float o = (sPxy[fr * 4 + 0] * e0 + sPxy[fr * 4 + 1] * e1 +
                             sPxy[fr * 4 + 2] * e2 + sPxy[fr * 4 + 3] * e3) * inv;
            out[row0g + fr] = o;
        }
    }
}

// ---------------------------------------------------------------------------
extern "C" void kernel_launch(void* const* d_in, const int* in_sizes, int n_in,
                              void* d_out, int out_size, void* d_ws, size_t ws_size,
                              hipStream_t stream)
{
    const float* depth = (const float*)d_in[0];
    const float* feat  = (const float*)d_in[1];
    const float* coord = (const float*)d_in[2];
    const float* pw0 = (const float*)d_in[3],  *pb0 = (const float*)d_in[4];
    const float* pw1 = (const float*)d_in[5],  *pb1 = (const float*)d_in[6];
    const float* pw2 = (const float*)d_in[7],  *pb2 = (const float*)d_in[8];
    const float* ew0 = (const float*)d_in[9],  *eb0 = (const float*)d_in[10];
    const float* ew1 = (const float*)d_in[11], *eb1 = (const float*)d_in[12];
    const float* ew2 = (const float*)d_in[13], *eb2 = (const float*)d_in[14];
    const float* ew3 = (const float*)d_in[15], *eb3 = (const float*)d_in[16];
    float* out = (float*)d_out;

    const size_t nhwc_bytes = (size_t)NBATCH * HWSZ * CC * 2;
    const size_t xy_bytes   = (size_t)NBATCH * HWSZ * 4;
    const size_t wt_bytes   = (size_t)WTOTAL * 2;
    const bool use_ws = (ws_size >= nhwc_bytes + xy_bytes + wt_bytes);

    ushort* nhwc = (ushort*)d_ws;
    float*  xyws = (float*)((char*)d_ws + nhwc_bytes);
    ushort* wt   = use_ws ? (ushort*)((char*)d_ws + nhwc_bytes + xy_bytes)
                          : (ushort*)d_ws;

    WPack pack;
    pack.d[0] = { pw0, 8,   64,  6 };
    pack.d[1] = { pw1, 64,  128, 6 };
    pack.d[2] = { pw2, 128, 256, 7 };
    pack.d[3] = { ew0, 256, 256, 8 };
    pack.d[4] = { ew1, 256, 128, 8 };
    pack.d[5] = { ew2, 128, 64,  7 };
    prep_weights<<<WTOTAL / 256, 256, 0, stream>>>(pack, wt);

    const int nblocks = (NBATCH * QQ) / ROWS;   // 4096

    if (use_ws) {
        prep_feat<<<(NBATCH * HWSZ) / 256, 256, 0, stream>>>(depth, feat, nhwc, xyws);
        fused_kernel<true><<<nblocks, THREADS, LDS_BYTES, stream>>>(
            depth, feat, coord, pb0, pb1, pb2, eb0, eb1, eb2, ew3, eb3,
            wt, nhwc, xyws, out);
    } else {
        fused_kernel<false><<<nblocks, THREADS, LDS_BYTES, stream>>>(
            depth, feat, coord, pb0, pb1, pb2, eb0, eb1, eb2, ew3, eb3,
            wt, nhwc, xyws, out);
    }
}

// Round 16
// 140.815 us; speedup vs baseline: 1.3251x; 1.3251x over previous
//
#include <hip/hip_runtime.h>
#include <hip/hip_runtime_api.h>
#include <math.h>

#define NBATCH 2
#define QQ     131072
#define HH     64
#define WWID   2048
#define CC     64
#define HWSZ   (HH*WWID)   /* 131072 = 2^17 */

constexpr int ROWS    = 64;    // rows per block
constexpr int THREADS = 256;   // 4 waves; wave tile = 64 rows x N/4 cols

// A: 64 rows x 512 B (256 bf16), XOR-swizzled; byte ^= (row&7)<<4
constexpr int ASTR_B = 512;

// dynamic-LDS byte offsets
constexpr int OFF_A   = 0;                 // 32768 B
constexpr int OFF_TAP = 32768;             // tap[64][4] int  = 1024 B
constexpr int OFF_PXY = OFF_TAP + 1024;    // pxy[64][4] f32  = 1024 B
constexpr int OFF_E3  = OFF_PXY + 1024;    // ew3 64x4 f32    = 1024 B
constexpr int LDS_BYTES = OFF_E3 + 1024;   // 35840 B

// packed fragment-layout weight offsets in elements (Kp = K padded to 64)
constexpr int WOFF_PE0 = 0;       // N=64,  Kp=64   -> 4096
constexpr int WOFF_PE1 = 4096;    // N=128, Kp=64   -> 8192
constexpr int WOFF_PE2 = 12288;   // N=256, Kp=128  -> 32768
constexpr int WOFF_E0  = 45056;   // N=256, Kp=256  -> 65536
constexpr int WOFF_E1  = 110592;  // N=128, Kp=256  -> 32768
constexpr int WOFF_E2  = 143360;  // N=64,  Kp=128  -> 8192
constexpr int WTOTAL   = 151552;

typedef __attribute__((ext_vector_type(8))) short bf16x8;
typedef __attribute__((ext_vector_type(4))) float f32x4;

__device__ __forceinline__ ushort f2bf(float f) {
    union { float f; unsigned u; } x; x.f = f;
    unsigned r = x.u + 0x7fffu + ((x.u >> 16) & 1u);   // RNE
    return (ushort)(r >> 16);
}
__device__ __forceinline__ float bf2f(ushort h) {
    union { unsigned u; float f; } x; x.u = ((unsigned)h) << 16;
    return x.f;
}
// pack 2 f32 -> 2 bf16 in one u32 (RNE, gfx950). lo = cvt(a), hi = cvt(b).
__device__ __forceinline__ unsigned cvtpk(float a, float b) {
    unsigned r;
    asm("v_cvt_pk_bf16_f32 %0, %1, %2" : "=v"(r) : "v"(a), "v"(b));
    return r;
}

// swizzled A byte address (XOR flips bits 4-6 by row)
__device__ __forceinline__ int swA(int row, int colByte) {
    return row * ASTR_B + (colByte ^ ((row & 7) << 4));
}

// ---------------------------------------------------------------------------
// Weight prep: fp32 [K][N] -> bf16 MFMA-fragment-packed [chunks][tiles][512]
// tile = 16 cols x 32 k, lane-ordered: elem(lane,j) = W[k0+(lane>>4)*8+j][n0+(lane&15)]
// chunk = 64 k-wide: tiles ordered (n>>4)*2 + kk
// ---------------------------------------------------------------------------
struct WDesc { const float* src; int K; int N; int kshift; };  // Kp = 1<<kshift
struct WPack { WDesc d[6]; };

__global__ __launch_bounds__(256) void prep_weights(WPack p, ushort* __restrict__ dst)
{
    int e = blockIdx.x * 256 + threadIdx.x;
    int off = 0;
    #pragma unroll
    for (int L = 0; L < 6; ++L) {
        const int Kp = 1 << p.d[L].kshift;
        const int N  = p.d[L].N;
        const int sz = N * Kp;
        if (e < sz) {
            const int n = e / Kp;
            const int k = e & (Kp - 1);
            const float v = (k < p.d[L].K) ? p.d[L].src[(size_t)k * N + n] : 0.f;
            const int chunk = k >> 6;
            const int kk    = (k >> 5) & 1;
            const int tile  = chunk * ((N >> 4) * 2) + (n >> 4) * 2 + kk;
            const int lane  = (n & 15) + (((k >> 3) & 3) << 4);
            const int j     = k & 7;
            dst[off + tile * 512 + lane * 8 + j] = f2bf(v);
            return;
        }
        e -= sz; off += sz;
    }
}

// ---------------------------------------------------------------------------
// Feat prep: NCHW f32 -> NHWC bf16, plus xy = sqrt(d1^2+d2^2)
// ---------------------------------------------------------------------------
__global__ __launch_bounds__(256) void prep_feat(
    const float* __restrict__ depth, const float* __restrict__ feat,
    ushort* __restrict__ nhwc, float* __restrict__ xy)
{
    const int idx = blockIdx.x * 256 + threadIdx.x;
    const int b   = idx >> 17;
    const int yx  = idx & (HWSZ - 1);

    const float d1 = depth[(b * 3 + 1) * HWSZ + yx];
    const float d2 = depth[(b * 3 + 2) * HWSZ + yx];
    xy[idx] = sqrtf(d1 * d1 + d2 * d2);

    const float* fp = feat + (size_t)b * CC * HWSZ + yx;
    ushort* op = nhwc + (size_t)idx * CC;
    #pragma unroll
    for (int c = 0; c < CC; c += 8) {
        union { uint4 v; ushort u[8]; } t;
        #pragma unroll
        for (int j = 0; j < 8; ++j) t.u[j] = f2bf(fp[(size_t)(c + j) * HWSZ]);
        *(uint4*)(op + c) = t.v;
    }
}

// ---------------------------------------------------------------------------
// One dense layer, in place on A (bf16, swizzled LDS). 4 waves split N.
// Wave tile 64 rows x N/4 cols: each B-fragment load feeds FOUR MFMAs.
// SWAPPED operands: mfma(w_frag, a_frag) -> lane holds 4 consecutive output
// cols of one row -> packed ds_write_b64 writeback. Weights load directly
// global->VGPR from fragment-packed wt (L1/L2-hot). (r14 structure — no
// chunk-loop unroll pragma, no gather fusion; both regressed in r15.)
// ---------------------------------------------------------------------------
template <int K, int N, bool RELU>
__device__ __forceinline__ void dense_layer(
    char* __restrict__ sA, const ushort* __restrict__ Wt,
    const float* __restrict__ Bg, int tid)
{
    constexpr int TN  = N / 64;        // 16-col tiles per wave
    constexpr int NCH = K / 64;        // 64-wide K chunks

    const int lane = tid & 63, wv = tid >> 6;   // wv in 0..3
    const int col0 = wv * (N / 4);
    const int lrow = lane & 15;
    const int lkb  = (lane >> 4) * 16;   // byte offset of this lane's 8 bf16 in k

    f32x4 acc[4][TN];
    #pragma unroll
    for (int tm = 0; tm < 4; ++tm)
        #pragma unroll
        for (int tn = 0; tn < TN; ++tn) acc[tm][tn] = (f32x4){0.f, 0.f, 0.f, 0.f};

    const char* wbase = (const char*)Wt + (size_t)lane * 16;

    for (int c = 0; c < NCH; ++c) {
        #pragma unroll
        for (int ks = 0; ks < 64; ks += 32) {
            const int cb = (c * 64 + ks) * 2 + lkb;
            const bf16x8 a0 = *(const bf16x8*)(sA + swA(     lrow, cb));
            const bf16x8 a1 = *(const bf16x8*)(sA + swA(16 + lrow, cb));
            const bf16x8 a2 = *(const bf16x8*)(sA + swA(32 + lrow, cb));
            const bf16x8 a3 = *(const bf16x8*)(sA + swA(48 + lrow, cb));
            #pragma unroll
            for (int tn = 0; tn < TN; ++tn) {
                const int tile = c * ((N >> 4) * 2) + ((col0 >> 4) + tn) * 2 + (ks >> 5);
                const bf16x8 bw = *(const bf16x8*)(wbase + tile * 1024);
                acc[0][tn] = __builtin_amdgcn_mfma_f32_16x16x32_bf16(bw, a0, acc[0][tn], 0, 0, 0);
                acc[1][tn] = __builtin_amdgcn_mfma_f32_16x16x32_bf16(bw, a1, acc[1][tn], 0, 0, 0);
                acc[2][tn] = __builtin_amdgcn_mfma_f32_16x16x32_bf16(bw, a2, acc[2][tn], 0, 0, 0);
                acc[3][tn] = __builtin_amdgcn_mfma_f32_16x16x32_bf16(bw, a3, acc[3][tn], 0, 0, 0);
            }
        }
    }
    __syncthreads();   // all waves done reading A -> safe in-place writeback

    // writeback: lane holds row = tm*16+lrow, cols = colb..colb+3
    #pragma unroll
    for (int tn = 0; tn < TN; ++tn) {
        const int colb = col0 + tn * 16 + (lane >> 4) * 4;
        const float4 b4 = *(const float4*)(Bg + colb);
        #pragma unroll
        for (int tm = 0; tm < 4; ++tm) {
            float v0 = acc[tm][tn][0] + b4.x;
            float v1 = acc[tm][tn][1] + b4.y;
            float v2 = acc[tm][tn][2] + b4.z;
            float v3 = acc[tm][tn][3] + b4.w;
            if (RELU) {
                v0 = fmaxf(v0, 0.f); v1 = fmaxf(v1, 0.f);
                v2 = fmaxf(v2, 0.f); v3 = fmaxf(v3, 0.f);
            }
            uint2 pk;
            pk.x = cvtpk(v0, v1);
            pk.y = cvtpk(v2, v3);
            const int row = tm * 16 + lrow;
            *(uint2*)(sA + swA(row, colb * 2)) = pk;
        }
    }
    __syncthreads();
}

// ---------------------------------------------------------------------------
// Fused: taps + PE MLP + gather-add + encoder MLP + softmax + output
// __launch_bounds__(256, 3): 168-reg unified budget (acc[4][4]=64 + ~84 arch).
// r14 structure exactly; only the final phase's LDS reads are vectorized
// (2x ds_read_b128 replaces 16x ds_read_u16 — swizzle preserves 16B blocks).
// ---------------------------------------------------------------------------
template <bool USE_WS>
__global__ __launch_bounds__(256, 3) void fused_kernel(
    const float* __restrict__ depth, const float* __restrict__ feat,
    const float* __restrict__ coord,
    const float* __restrict__ pb0, const float* __restrict__ pb1,
    const float* __restrict__ pb2,
    const float* __restrict__ eb0, const float* __restrict__ eb1,
    const float* __restrict__ eb2,
    const float* __restrict__ ew3, const float* __restrict__ eb3,
    const ushort* __restrict__ wt,
    const ushort* __restrict__ nhwc, const float* __restrict__ xyws,
    float* __restrict__ out)
{
    extern __shared__ char lds[];
    char*  sA   = lds + OFF_A;
    int*   sTap = (int*)(lds + OFF_TAP);
    float* sPxy = (float*)(lds + OFF_PXY);
    float* sE3  = (float*)(lds + OFF_E3);

    const int tid  = threadIdx.x;
    const int row0g = blockIdx.x * ROWS;
    const int b     = row0g >> 17;   // QQ = 2^17, ROWS | QQ

    // stage final-layer weights (64x4 f32)
    sE3[tid] = ew3[tid];

    // zero A cols 0..63 (pe0 K padded 8->64); swizzle permutes within bytes 0..127
    {
        const int r = tid >> 2, q = tid & 3;
        uint4 z; z.x = z.y = z.z = z.w = 0u;
        *(uint4*)(sA + r * ASTR_B + q * 32)      = z;
        *(uint4*)(sA + r * ASTR_B + q * 32 + 16) = z;
    }
    __syncthreads();

    // taps + rel coords + pred_xy; fp32, contraction OFF (match numpy rounding)
    {
        #pragma clang fp contract(off)
        const int r = tid >> 2, s = tid & 3;
        const int row = row0g + r;
        const float cy = coord[row * 2 + 0];
        const float cx = coord[row * 2 + 1];
        const float offy = (s < 2) ? -1.f : 1.f;
        const float offx = (s & 1) ? 1.f : -1.f;
        const float rx = 1.f / (float)HH, ry = 1.f / (float)WWID;
        float ccy = cy + (offy * rx + 1e-6f);
        float ccx = cx + (offx * ry + 1e-6f);
        ccy = fminf(fmaxf(ccy, -1.f + 1e-6f), 1.f - 1e-6f);
        ccx = fminf(fmaxf(ccx, -1.f + 1e-6f), 1.f - 1e-6f);
        int iy = (int)rintf(((ccy + 1.f) * (float)HH - 1.f) * 0.5f);
        int ix = (int)rintf(((ccx + 1.f) * (float)WWID - 1.f) * 0.5f);
        iy = min(max(iy, 0), HH - 1);
        ix = min(max(ix, 0), WWID - 1);
        const float qcy = -1.f + (2.f * (float)iy + 1.f) / (float)HH;
        const float qcx = -1.f + (2.f * (float)ix + 1.f) / (float)WWID;
        *(ushort*)(sA + swA(r, s * 4 + 0)) = f2bf((cy - qcy) * (float)HH);
        *(ushort*)(sA + swA(r, s * 4 + 2)) = f2bf((cx - qcx) * (float)WWID);
        const int tap = iy * WWID + ix;
        sTap[r * 4 + s] = tap;
        float px;
        if (USE_WS) {
            px = xyws[b * HWSZ + tap];
        } else {
            const float d1 = depth[(b * 3 + 1) * HWSZ + tap];
            const float d2 = depth[(b * 3 + 2) * HWSZ + tap];
            px = sqrtf(d1 * d1 + d2 * d2);
        }
        sPxy[r * 4 + s] = px;
    }
    __syncthreads();

    // PE MLP (rel coords in A cols 0..7, zero-padded to 64)
    dense_layer<64,  64,  true >(sA, wt + WOFF_PE0, pb0, tid);
    dense_layer<64,  128, true >(sA, wt + WOFF_PE1, pb1, tid);
    dense_layer<128, 256, false>(sA, wt + WOFF_PE2, pb2, tid);

    // gather-add q_feat: A[r][s*64+c] += feat[b,c,tap]; thread = (row, tap)
    {
        const int gr = tid >> 2, gs = tid & 3;
        const int tap = sTap[gr * 4 + gs];
        const int cb0 = gs * 128;   // byte offset of this tap's 64 channels
        if (USE_WS) {
            const ushort* src = nhwc + ((size_t)b * HWSZ + tap) * CC;
            #pragma unroll
            for (int g = 0; g < 8; ++g) {
                char* dp = sA + swA(gr, cb0 + g * 16);
                union { uint4 v; ushort u[8]; } a, d;
                a.v = *(const uint4*)(src + g * 8);
                d.v = *(uint4*)dp;
                float s0 = bf2f(a.u[0]) + bf2f(d.u[0]);
                float s1 = bf2f(a.u[1]) + bf2f(d.u[1]);
                float s2 = bf2f(a.u[2]) + bf2f(d.u[2]);
                float s3 = bf2f(a.u[3]) + bf2f(d.u[3]);
                float s4 = bf2f(a.u[4]) + bf2f(d.u[4]);
                float s5 = bf2f(a.u[5]) + bf2f(d.u[5]);
                float s6 = bf2f(a.u[6]) + bf2f(d.u[6]);
                float s7 = bf2f(a.u[7]) + bf2f(d.u[7]);
                uint4 o;
                o.x = cvtpk(s0, s1); o.y = cvtpk(s2, s3);
                o.z = cvtpk(s4, s5); o.w = cvtpk(s6, s7);
                *(uint4*)dp = o;
            }
        } else {
            const float* fp = feat + (size_t)b * CC * HWSZ + tap;
            #pragma unroll 8
            for (int c = 0; c < CC; ++c) {
                ushort* p = (ushort*)(sA + swA(gr, cb0 + c * 2));
                *p = f2bf(bf2f(*p) + fp[(size_t)c * HWSZ]);
            }
        }
    }
    __syncthreads();

    // encoder MLP
    dense_layer<256, 256, true>(sA, wt + WOFF_E0, eb0, tid);
    dense_layer<256, 128, true>(sA, wt + WOFF_E1, eb1, tid);
    dense_layer<128, 64,  true>(sA, wt + WOFF_E2, eb2, tid);

    // final 64->4, softmax, weighted sum with pred_xy (4 threads per row).
    // Thread sub covers cols sub*16..sub*16+15 = two swizzled 16B LDS blocks.
    {
        const int fr = tid >> 2, sub = tid & 3;
        union { uint4 v; ushort u[8]; } h0, h1;
        h0.v = *(const uint4*)(sA + swA(fr, sub * 32));
        h1.v = *(const uint4*)(sA + swA(fr, sub * 32 + 16));
        float l0 = 0.f, l1 = 0.f, l2 = 0.f, l3 = 0.f;
        #pragma unroll
        for (int kk = 0; kk < 8; ++kk) {
            const float a = bf2f(h0.u[kk]);
            const float4 w = ((const float4*)sE3)[sub * 16 + kk];
            l0 = fmaf(a, w.x, l0);
            l1 = fmaf(a, w.y, l1);
            l2 = fmaf(a, w.z, l2);
            l3 = fmaf(a, w.w, l3);
        }
        #pragma unroll
        for (int kk = 0; kk < 8; ++kk) {
            const float a = bf2f(h1.u[kk]);
            const float4 w = ((const float4*)sE3)[sub * 16 + 8 + kk];
            l0 = fmaf(a, w.x, l0);
            l1 = fmaf(a, w.y, l1);
            l2 = fmaf(a, w.z, l2);
            l3 = fmaf(a, w.w, l3);
        }
        #pragma unroll
        for (int m = 1; m <= 2; m <<= 1) {
            l0 += __shfl_xor(l0, m);
            l1 += __shfl_xor(l1, m);
            l2 += __shfl_xor(l2, m);
            l3 += __shfl_xor(l3, m);
        }
        if (sub == 0) {
            l0 += eb3[0]; l1 += eb3[1]; l2 += eb3[2]; l3 += eb3[3];
            const float m  = fmaxf(fmaxf(l0, l1), fmaxf(l2, l3));
            const float e0 = expf(l0 - m), e1 = expf(l1 - m);
            const float e2 = expf(l2 - m), e3 = expf(l3 - m);
            const float inv = 1.f / (e0 + e1 + e2 + e3);
            const float o = (sPxy[fr * 4 + 0] * e0 + sPxy[fr * 4 + 1] * e1 +
                             sPxy[fr * 4 + 2] * e2 + sPxy[fr * 4 + 3] * e3) * inv;
            out[row0g + fr] = o;
        }
    }
}

// ---------------------------------------------------------------------------
extern "C" void kernel_launch(void* const* d_in, const int* in_sizes, int n_in,
                              void* d_out, int out_size, void* d_ws, size_t ws_size,
                              hipStream_t stream)
{
    const float* depth = (const float*)d_in[0];
    const float* feat  = (const float*)d_in[1];
    const float* coord = (const float*)d_in[2];
    const float* pw0 = (const float*)d_in[3],  *pb0 = (const float*)d_in[4];
    const float* pw1 = (const float*)d_in[5],  *pb1 = (const float*)d_in[6];
    const float* pw2 = (const float*)d_in[7],  *pb2 = (const float*)d_in[8];
    const float* ew0 = (const float*)d_in[9],  *eb0 = (const float*)d_in[10];
    const float* ew1 = (const float*)d_in[11], *eb1 = (const float*)d_in[12];
    const float* ew2 = (const float*)d_in[13], *eb2 = (const float*)d_in[14];
    const float* ew3 = (const float*)d_in[15], *eb3 = (const float*)d_in[16];
    float* out = (float*)d_out;

    const size_t nhwc_bytes = (size_t)NBATCH * HWSZ * CC * 2;
    const size_t xy_bytes   = (size_t)NBATCH * HWSZ * 4;
    const size_t wt_bytes   = (size_t)WTOTAL * 2;
    const bool use_ws = (ws_size >= nhwc_bytes + xy_bytes + wt_bytes);

    ushort* nhwc = (ushort*)d_ws;
    float*  xyws = (float*)((char*)d_ws + nhwc_bytes);
    ushort* wt   = use_ws ? (ushort*)((char*)d_ws + nhwc_bytes + xy_bytes)
                          : (ushort*)d_ws;

    WPack pack;
    pack.d[0] = { pw0, 8,   64,  6 };
    pack.d[1] = { pw1, 64,  128, 6 };
    pack.d[2] = { pw2, 128, 256, 7 };
    pack.d[3] = { ew0, 256, 256, 8 };
    pack.d[4] = { ew1, 256, 128, 8 };
    pack.d[5] = { ew2, 128, 64,  7 };
    prep_weights<<<WTOTAL / 256, 256, 0, stream>>>(pack, wt);

    const int nblocks = (NBATCH * QQ) / ROWS;   // 4096

    if (use_ws) {
        prep_feat<<<(NBATCH * HWSZ) / 256, 256, 0, stream>>>(depth, feat, nhwc, xyws);
        fused_kernel<true><<<nblocks, THREADS, LDS_BYTES, stream>>>(
            depth, feat, coord, pb0, pb1, pb2, eb0, eb1, eb2, ew3, eb3,
            wt, nhwc, xyws, out);
    } else {
        fused_kernel<false><<<nblocks, THREADS, LDS_BYTES, stream>>>(
            depth, feat, coord, pb0, pb1, pb2, eb0, eb1, eb2, ew3, eb3,
            wt, nhwc, xyws, out);
    }
}

// Round 17
// 139.650 us; speedup vs baseline: 1.3361x; 1.0083x over previous
//
#include <hip/hip_runtime.h>
#include <hip/hip_runtime_api.h>
#include <math.h>

#define NBATCH 2
#define QQ     131072
#define HH     64
#define WWID   2048
#define CC     64
#define HWSZ   (HH*WWID)   /* 131072 = 2^17 */

constexpr int ROWS    = 64;    // rows per block
constexpr int THREADS = 256;   // 4 waves

// A: 64 rows x 512 B (256 bf16), XOR-swizzled; byte ^= (row&15)<<4
constexpr int ASTR_B = 512;

// dynamic-LDS byte offsets
constexpr int OFF_A   = 0;                 // 32768 B
constexpr int OFF_TAP = 32768;             // tap[64][4] int  = 1024 B
constexpr int OFF_PXY = OFF_TAP + 1024;    // pxy[64][4] f32  = 1024 B
constexpr int OFF_E3  = OFF_PXY + 1024;    // ew3 64x4 f32    = 1024 B
constexpr int LDS_BYTES = OFF_E3 + 1024;   // 35840 B

// packed fragment-layout weight offsets in elements (Kp = K padded to 16-mult)
// tile = 32 cols x 16 k (1 KB): elem(lane,j) = W[k0+(lane>>5)*8+j][n0+(lane&31)]
// tiles ordered kstep-major: tile = kstep*(N/32) + n32
constexpr int WOFF_PE0 = 0;        // N=64,  Kp=16  -> 1024
constexpr int WOFF_PE1 = 1024;     // N=128, Kp=64  -> 8192
constexpr int WOFF_PE2 = 9216;     // N=256, Kp=128 -> 32768
constexpr int WOFF_E0  = 41984;    // N=256, Kp=256 -> 65536
constexpr int WOFF_E1  = 107520;   // N=128, Kp=256 -> 32768
constexpr int WOFF_E2  = 140288;   // N=64,  Kp=128 -> 8192
constexpr int WTOTAL   = 148480;   // 580 * 256

typedef __attribute__((ext_vector_type(8)))  short bf16x8;
typedef __attribute__((ext_vector_type(16))) float f32x16;

__device__ __forceinline__ ushort f2bf(float f) {
    union { float f; unsigned u; } x; x.f = f;
    unsigned r = x.u + 0x7fffu + ((x.u >> 16) & 1u);   // RNE
    return (ushort)(r >> 16);
}
__device__ __forceinline__ float bf2f(ushort h) {
    union { unsigned u; float f; } x; x.u = ((unsigned)h) << 16;
    return x.f;
}
// pack 2 f32 -> 2 bf16 in one u32 (RNE, gfx950). lo = cvt(a), hi = cvt(b).
__device__ __forceinline__ unsigned cvtpk(float a, float b) {
    unsigned r;
    asm("v_cvt_pk_bf16_f32 %0, %1, %2" : "=v"(r) : "v"(a), "v"(b));
    return r;
}

// swizzled A byte address (XOR flips bits 4-7 by row; 16B blocks preserved)
__device__ __forceinline__ int swA(int row, int colByte) {
    return row * ASTR_B + (colByte ^ ((row & 15) << 4));
}

// ---------------------------------------------------------------------------
// Weight prep: fp32 [K][N] -> bf16 packed for 32x32x16 swapped-operand MFMA.
// ---------------------------------------------------------------------------
struct WDesc { const float* src; int K; int N; int kshift; };  // Kp = 1<<kshift
struct WPack { WDesc d[6]; };

__global__ __launch_bounds__(256) void prep_weights(WPack p, ushort* __restrict__ dst)
{
    int e = blockIdx.x * 256 + threadIdx.x;
    int off = 0;
    #pragma unroll
    for (int L = 0; L < 6; ++L) {
        const int Kp = 1 << p.d[L].kshift;
        const int N  = p.d[L].N;
        const int sz = N * Kp;
        if (e < sz) {
            const int n = e / Kp;
            const int k = e & (Kp - 1);
            const float v = (k < p.d[L].K) ? p.d[L].src[(size_t)k * N + n] : 0.f;
            const int kstep = k >> 4;
            const int tile  = kstep * (N >> 5) + (n >> 5);
            const int lane  = (n & 31) | (((k >> 3) & 1) << 5);
            const int j     = k & 7;
            dst[off + tile * 512 + lane * 8 + j] = f2bf(v);
            return;
        }
        e -= sz; off += sz;
    }
}

// ---------------------------------------------------------------------------
// Feat prep: NCHW f32 -> NHWC bf16, plus xy = sqrt(d1^2+d2^2)
// ---------------------------------------------------------------------------
__global__ __launch_bounds__(256) void prep_feat(
    const float* __restrict__ depth, const float* __restrict__ feat,
    ushort* __restrict__ nhwc, float* __restrict__ xy)
{
    const int idx = blockIdx.x * 256 + threadIdx.x;
    const int b   = idx >> 17;
    const int yx  = idx & (HWSZ - 1);

    const float d1 = depth[(b * 3 + 1) * HWSZ + yx];
    const float d2 = depth[(b * 3 + 2) * HWSZ + yx];
    xy[idx] = sqrtf(d1 * d1 + d2 * d2);

    const float* fp = feat + (size_t)b * CC * HWSZ + yx;
    ushort* op = nhwc + (size_t)idx * CC;
    #pragma unroll
    for (int c = 0; c < CC; c += 8) {
        union { uint4 v; ushort u[8]; } t;
        #pragma unroll
        for (int j = 0; j < 8; ++j) t.u[j] = f2bf(fp[(size_t)(c + j) * HWSZ]);
        *(uint4*)(op + c) = t.v;
    }
}

// ---------------------------------------------------------------------------
// One dense layer, in place on A (bf16, swizzled LDS), 32x32x16 MFMA with
// SWAPPED operands: mfma(w_frag, act_frag). D: output col = (reg&3)+8*(reg>>2)
// +4*(lane>>5), act row = lane&31 -> packed uint2 writeback per 4 cols.
// Wave grid: N=256: 64r x 64c (CT=2); N=128: 64r x 32c; N=64: 32r x 32c (2Mx2N).
// Weights load directly global->VGPR from fragment-packed wt (L1/L2-hot).
// ---------------------------------------------------------------------------
template <int K, int N, bool RELU>
__device__ __forceinline__ void dense_layer(
    char* __restrict__ sA, const ushort* __restrict__ Wt,
    const float* __restrict__ Bg, int tid)
{
    constexpr int CT = (N == 256) ? 2 : 1;   // 32-col tiles per wave
    constexpr int RG = (N == 64) ? 1 : 2;    // 32-row groups per wave
    constexpr int KS = K / 16;               // 16-wide k steps

    const int lane = tid & 63, wv = tid >> 6;   // wv in 0..3
    const int row0 = (N == 64) ? (wv >> 1) * 32 : 0;
    const int col0 = (N == 64) ? (wv & 1) * 32 : wv * (N / 4);
    const int lrow = lane & 31;
    const int lkb  = (lane >> 5) * 16;   // byte offset of this lane's 8 bf16 in k

    f32x16 acc[RG][CT];
    #pragma unroll
    for (int rg = 0; rg < RG; ++rg)
        #pragma unroll
        for (int ct = 0; ct < CT; ++ct)
            #pragma unroll
            for (int t = 0; t < 16; ++t) acc[rg][ct][t] = 0.f;

    const char* wbase = (const char*)Wt + (size_t)lane * 16;

    for (int kst = 0; kst < KS; ++kst) {
        const int cb = kst * 32 + lkb;
        bf16x8 a[RG];
        #pragma unroll
        for (int rg = 0; rg < RG; ++rg)
            a[rg] = *(const bf16x8*)(sA + swA(row0 + rg * 32 + lrow, cb));
        #pragma unroll
        for (int ct = 0; ct < CT; ++ct) {
            const int tile = kst * (N >> 5) + (col0 >> 5) + ct;
            const bf16x8 bw = *(const bf16x8*)(wbase + tile * 1024);
            #pragma unroll
            for (int rg = 0; rg < RG; ++rg)
                acc[rg][ct] = __builtin_amdgcn_mfma_f32_32x32x16_bf16(bw, a[rg], acc[rg][ct], 0, 0, 0);
        }
    }
    __syncthreads();   // all waves done reading A -> safe in-place writeback

    // writeback: lane holds act row = row0+rg*32+(lane&31),
    // cols = col0 + ct*32 + 8q + 4*(lane>>5) + {0..3} from acc[rg][ct][4q..4q+3]
    #pragma unroll
    for (int ct = 0; ct < CT; ++ct) {
        #pragma unroll
        for (int q = 0; q < 4; ++q) {
            const int colb = col0 + ct * 32 + q * 8 + (lane >> 5) * 4;
            const float4 b4 = *(const float4*)(Bg + colb);
            #pragma unroll
            for (int rg = 0; rg < RG; ++rg) {
                float v0 = acc[rg][ct][q * 4 + 0] + b4.x;
                float v1 = acc[rg][ct][q * 4 + 1] + b4.y;
                float v2 = acc[rg][ct][q * 4 + 2] + b4.z;
                float v3 = acc[rg][ct][q * 4 + 3] + b4.w;
                if (RELU) {
                    v0 = fmaxf(v0, 0.f); v1 = fmaxf(v1, 0.f);
                    v2 = fmaxf(v2, 0.f); v3 = fmaxf(v3, 0.f);
                }
                uint2 pk;
                pk.x = cvtpk(v0, v1);
                pk.y = cvtpk(v2, v3);
                const int row = row0 + rg * 32 + lrow;
                *(uint2*)(sA + swA(row, colb * 2)) = pk;
            }
        }
    }
    __syncthreads();
}

// ---------------------------------------------------------------------------
// Fused: taps + PE MLP + gather-add + encoder MLP + softmax + output
// __launch_bounds__(256, 3): 168-reg unified budget (acc 64 + ~84 arch).
// ---------------------------------------------------------------------------
template <bool USE_WS>
__global__ __launch_bounds__(256, 3) void fused_kernel(
    const float* __restrict__ depth, const float* __restrict__ feat,
    const float* __restrict__ coord,
    const float* __restrict__ pb0, const float* __restrict__ pb1,
    const float* __restrict__ pb2,
    const float* __restrict__ eb0, const float* __restrict__ eb1,
    const float* __restrict__ eb2,
    const float* __restrict__ ew3, const float* __restrict__ eb3,
    const ushort* __restrict__ wt,
    const ushort* __restrict__ nhwc, const float* __restrict__ xyws,
    float* __restrict__ out)
{
    extern __shared__ char lds[];
    char*  sA   = lds + OFF_A;
    int*   sTap = (int*)(lds + OFF_TAP);
    float* sPxy = (float*)(lds + OFF_PXY);
    float* sE3  = (float*)(lds + OFF_E3);

    const int tid  = threadIdx.x;
    const int row0g = blockIdx.x * ROWS;
    const int b     = row0g >> 17;   // QQ = 2^17, ROWS | QQ

    // stage final-layer weights (64x4 f32)
    sE3[tid] = ew3[tid];

    // taps + rel coords + pred_xy; fp32, contraction OFF (match numpy rounding)
    {
        #pragma clang fp contract(off)
        const int r = tid >> 2, s = tid & 3;
        const int row = row0g + r;
        const float cy = coord[row * 2 + 0];
        const float cx = coord[row * 2 + 1];
        const float offy = (s < 2) ? -1.f : 1.f;
        const float offx = (s & 1) ? 1.f : -1.f;
        const float rx = 1.f / (float)HH, ry = 1.f / (float)WWID;
        float ccy = cy + (offy * rx + 1e-6f);
        float ccx = cx + (offx * ry + 1e-6f);
        ccy = fminf(fmaxf(ccy, -1.f + 1e-6f), 1.f - 1e-6f);
        ccx = fminf(fmaxf(ccx, -1.f + 1e-6f), 1.f - 1e-6f);
        int iy = (int)rintf(((ccy + 1.f) * (float)HH - 1.f) * 0.5f);
        int ix = (int)rintf(((ccx + 1.f) * (float)WWID - 1.f) * 0.5f);
        iy = min(max(iy, 0), HH - 1);
        ix = min(max(ix, 0), WWID - 1);
        const float qcy = -1.f + (2.f * (float)iy + 1.f) / (float)HH;
        const float qcx = -1.f + (2.f * (float)ix + 1.f) / (float)WWID;
        // rel coords -> A cols 2s, 2s+1 (bytes s*4..s*4+3; XOR only touches bits>=4)
        *(ushort*)(sA + swA(r, s * 4 + 0)) = f2bf((cy - qcy) * (float)HH);
        *(ushort*)(sA + swA(r, s * 4 + 2)) = f2bf((cx - qcx) * (float)WWID);
        // zero cols 8..15 (pe0 Kp=16; lanes>=32 read them, weightx0 still NaN-unsafe)
        if (s == 0) {
            uint4 z; z.x = z.y = z.z = z.w = 0u;
            *(uint4*)(sA + swA(r, 16)) = z;
        }
        const int tap = iy * WWID + ix;
        sTap[r * 4 + s] = tap;
        float px;
        if (USE_WS) {
            px = xyws[b * HWSZ + tap];
        } else {
            const float d1 = depth[(b * 3 + 1) * HWSZ + tap];
            const float d2 = depth[(b * 3 + 2) * HWSZ + tap];
            px = sqrtf(d1 * d1 + d2 * d2);
        }
        sPxy[r * 4 + s] = px;
    }
    __syncthreads();

    // PE MLP (rel coords in A cols 0..7, zero-padded to 16)
    dense_layer<16,  64,  true >(sA, wt + WOFF_PE0, pb0, tid);
    dense_layer<64,  128, true >(sA, wt + WOFF_PE1, pb1, tid);
    dense_layer<128, 256, false>(sA, wt + WOFF_PE2, pb2, tid);

    // gather-add q_feat: A[r][s*64+c] += feat[b,c,tap]; thread = (row, tap)
    {
        const int gr = tid >> 2, gs = tid & 3;
        const int tap = sTap[gr * 4 + gs];
        const int cb0 = gs * 128;   // byte offset of this tap's 64 channels
        if (USE_WS) {
            const ushort* src = nhwc + ((size_t)b * HWSZ + tap) * CC;
            #pragma unroll
            for (int g = 0; g < 8; ++g) {
                char* dp = sA + swA(gr, cb0 + g * 16);
                union { uint4 v; ushort u[8]; } a, d;
                a.v = *(const uint4*)(src + g * 8);
                d.v = *(uint4*)dp;
                float s0 = bf2f(a.u[0]) + bf2f(d.u[0]);
                float s1 = bf2f(a.u[1]) + bf2f(d.u[1]);
                float s2 = bf2f(a.u[2]) + bf2f(d.u[2]);
                float s3 = bf2f(a.u[3]) + bf2f(d.u[3]);
                float s4 = bf2f(a.u[4]) + bf2f(d.u[4]);
                float s5 = bf2f(a.u[5]) + bf2f(d.u[5]);
                float s6 = bf2f(a.u[6]) + bf2f(d.u[6]);
                float s7 = bf2f(a.u[7]) + bf2f(d.u[7]);
                uint4 o;
                o.x = cvtpk(s0, s1); o.y = cvtpk(s2, s3);
                o.z = cvtpk(s4, s5); o.w = cvtpk(s6, s7);
                *(uint4*)dp = o;
            }
        } else {
            const float* fp = feat + (size_t)b * CC * HWSZ + tap;
            #pragma unroll 8
            for (int c = 0; c < CC; ++c) {
                ushort* p = (ushort*)(sA + swA(gr, cb0 + c * 2));
                *p = f2bf(bf2f(*p) + fp[(size_t)c * HWSZ]);
            }
        }
    }
    __syncthreads();

    // encoder MLP
    dense_layer<256, 256, true>(sA, wt + WOFF_E0, eb0, tid);
    dense_layer<256, 128, true>(sA, wt + WOFF_E1, eb1, tid);
    dense_layer<128, 64,  true>(sA, wt + WOFF_E2, eb2, tid);

    // final 64->4, softmax, weighted sum with pred_xy (4 threads per row).
    // Thread sub covers cols sub*16..sub*16+15 = two swizzled 16B LDS blocks.
    {
        const int fr = tid >> 2, sub = tid & 3;
        union { uint4 v; ushort u[8]; } h0, h1;
        h0.v = *(const uint4*)(sA + swA(fr, sub * 32));
        h1.v = *(const uint4*)(sA + swA(fr, sub * 32 + 16));
        float l0 = 0.f, l1 = 0.f, l2 = 0.f, l3 = 0.f;
        #pragma unroll
        for (int kk = 0; kk < 8; ++kk) {
            const float a = bf2f(h0.u[kk]);
            const float4 w = ((const float4*)sE3)[sub * 16 + kk];
            l0 = fmaf(a, w.x, l0);
            l1 = fmaf(a, w.y, l1);
            l2 = fmaf(a, w.z, l2);
            l3 = fmaf(a, w.w, l3);
        }
        #pragma unroll
        for (int kk = 0; kk < 8; ++kk) {
            const float a = bf2f(h1.u[kk]);
            const float4 w = ((const float4*)sE3)[sub * 16 + 8 + kk];
            l0 = fmaf(a, w.x, l0);
            l1 = fmaf(a, w.y, l1);
            l2 = fmaf(a, w.z, l2);
            l3 = fmaf(a, w.w, l3);
        }
        #pragma unroll
        for (int m = 1; m <= 2; m <<= 1) {
            l0 += __shfl_xor(l0, m);
            l1 += __shfl_xor(l1, m);
            l2 += __shfl_xor(l2, m);
            l3 += __shfl_xor(l3, m);
        }
        if (sub == 0) {
            l0 += eb3[0]; l1 += eb3[1]; l2 += eb3[2]; l3 += eb3[3];
            const float m  = fmaxf(fmaxf(l0, l1), fmaxf(l2, l3));
            const float e0 = expf(l0 - m), e1 = expf(l1 - m);
            const float e2 = expf(l2 - m), e3 = expf(l3 - m);
            const float inv = 1.f / (e0 + e1 + e2 + e3);
            const float o = (sPxy[fr * 4 + 0] * e0 + sPxy[fr * 4 + 1] * e1 +
                             sPxy[fr * 4 + 2] * e2 + sPxy[fr * 4 + 3] * e3) * inv;
            out[row0g + fr] = o;
        }
    }
}

// ---------------------------------------------------------------------------
extern "C" void kernel_launch(void* const* d_in, const int* in_sizes, int n_in,
                              void* d_out, int out_size, void* d_ws, size_t ws_size,
                              hipStream_t stream)
{
    const float* depth = (const float*)d_in[0];
    const float* feat  = (const float*)d_in[1];
    const float* coord = (const float*)d_in[2];
    const float* pw0 = (const float*)d_in[3],  *pb0 = (const float*)d_in[4];
    const float* pw1 = (const float*)d_in[5],  *pb1 = (const float*)d_in[6];
    const float* pw2 = (const float*)d_in[7],  *pb2 = (const float*)d_in[8];
    const float* ew0 = (const float*)d_in[9],  *eb0 = (const float*)d_in[10];
    const float* ew1 = (const float*)d_in[11], *eb1 = (const float*)d_in[12];
    const float* ew2 = (const float*)d_in[13], *eb2 = (const float*)d_in[14];
    const float* ew3 = (const float*)d_in[15], *eb3 = (const float*)d_in[16];
    float* out = (float*)d_out;

    const size_t nhwc_bytes = (size_t)NBATCH * HWSZ * CC * 2;
    const size_t xy_bytes   = (size_t)NBATCH * HWSZ * 4;
    const size_t wt_bytes   = (size_t)WTOTAL * 2;
    const bool use_ws = (ws_size >= nhwc_bytes + xy_bytes + wt_bytes);

    ushort* nhwc = (ushort*)d_ws;
    float*  xyws = (float*)((char*)d_ws + nhwc_bytes);
    ushort* wt   = use_ws ? (ushort*)((char*)d_ws + nhwc_bytes + xy_bytes)
                          : (ushort*)d_ws;

    WPack pack;
    pack.d[0] = { pw0, 8,   64,  4 };
    pack.d[1] = { pw1, 64,  128, 6 };
    pack.d[2] = { pw2, 128, 256, 7 };
    pack.d[3] = { ew0, 256, 256, 8 };
    pack.d[4] = { ew1, 256, 128, 8 };
    pack.d[5] = { ew2, 128, 64,  7 };
    prep_weights<<<WTOTAL / 256, 256, 0, stream>>>(pack, wt);

    const int nblocks = (NBATCH * QQ) / ROWS;   // 4096

    if (use_ws) {
        prep_feat<<<(NBATCH * HWSZ) / 256, 256, 0, stream>>>(depth, feat, nhwc, xyws);
        fused_kernel<true><<<nblocks, THREADS, LDS_BYTES, stream>>>(
            depth, feat, coord, pb0, pb1, pb2, eb0, eb1, eb2, ew3, eb3,
            wt, nhwc, xyws, out);
    } else {
        fused_kernel<false><<<nblocks, THREADS, LDS_BYTES, stream>>>(
            depth, feat, coord, pb0, pb1, pb2, eb0, eb1, eb2, ew3, eb3,
            wt, nhwc, xyws, out);
    }
}

// Round 18
// 137.348 us; speedup vs baseline: 1.3585x; 1.0168x over previous
//
#include <hip/hip_runtime.h>
#include <hip/hip_runtime_api.h>
#include <math.h>

#define NBATCH 2
#define QQ     131072
#define HH     64
#define WWID   2048
#define CC     64
#define HWSZ   (HH*WWID)   /* 131072 = 2^17 */

constexpr int ROWS    = 128;   // rows per block
constexpr int THREADS = 256;   // 4 waves

// A: 128 rows x 512 B (256 bf16), XOR-swizzled; byte ^= (row&15)<<4
constexpr int ASTR_B = 512;

// dynamic-LDS byte offsets
constexpr int OFF_A   = 0;                 // 65536 B
constexpr int OFF_TAP = 65536;             // tap[128][4] int  = 2048 B
constexpr int OFF_PXY = OFF_TAP + 2048;    // pxy[128][4] f32  = 2048 B
constexpr int OFF_E3  = OFF_PXY + 2048;    // ew3 64x4 f32     = 1024 B
constexpr int LDS_BYTES = OFF_E3 + 1024;   // 70656 B -> 2 blocks/CU

// packed fragment-layout weight offsets in elements (Kp = K padded to 16-mult)
// tile = 32 cols x 16 k (1 KB): elem(lane,j) = W[k0+(lane>>5)*8+j][n0+(lane&31)]
// tiles ordered kstep-major: tile = kstep*(N/32) + n32
constexpr int WOFF_PE0 = 0;        // N=64,  Kp=16  -> 1024
constexpr int WOFF_PE1 = 1024;     // N=128, Kp=64  -> 8192
constexpr int WOFF_PE2 = 9216;     // N=256, Kp=128 -> 32768
constexpr int WOFF_E0  = 41984;    // N=256, Kp=256 -> 65536
constexpr int WOFF_E1  = 107520;   // N=128, Kp=256 -> 32768
constexpr int WOFF_E2  = 140288;   // N=64,  Kp=128 -> 8192
constexpr int WTOTAL   = 148480;   // 580 * 256

typedef __attribute__((ext_vector_type(8)))  short bf16x8;
typedef __attribute__((ext_vector_type(16))) float f32x16;

__device__ __forceinline__ ushort f2bf(float f) {
    union { float f; unsigned u; } x; x.f = f;
    unsigned r = x.u + 0x7fffu + ((x.u >> 16) & 1u);   // RNE
    return (ushort)(r >> 16);
}
__device__ __forceinline__ float bf2f(ushort h) {
    union { unsigned u; float f; } x; x.u = ((unsigned)h) << 16;
    return x.f;
}
// pack 2 f32 -> 2 bf16 in one u32 (RNE, gfx950). lo = cvt(a), hi = cvt(b).
__device__ __forceinline__ unsigned cvtpk(float a, float b) {
    unsigned r;
    asm("v_cvt_pk_bf16_f32 %0, %1, %2" : "=v"(r) : "v"(a), "v"(b));
    return r;
}

// swizzled A byte address (XOR flips bits 4-7 by row; 16B blocks preserved)
__device__ __forceinline__ int swA(int row, int colByte) {
    return row * ASTR_B + (colByte ^ ((row & 15) << 4));
}

// ---------------------------------------------------------------------------
// Weight prep: fp32 [K][N] -> bf16 packed for 32x32x16 swapped-operand MFMA.
// ---------------------------------------------------------------------------
struct WDesc { const float* src; int K; int N; int kshift; };  // Kp = 1<<kshift
struct WPack { WDesc d[6]; };

__global__ __launch_bounds__(256) void prep_weights(WPack p, ushort* __restrict__ dst)
{
    int e = blockIdx.x * 256 + threadIdx.x;
    int off = 0;
    #pragma unroll
    for (int L = 0; L < 6; ++L) {
        const int Kp = 1 << p.d[L].kshift;
        const int N  = p.d[L].N;
        const int sz = N * Kp;
        if (e < sz) {
            const int n = e / Kp;
            const int k = e & (Kp - 1);
            const float v = (k < p.d[L].K) ? p.d[L].src[(size_t)k * N + n] : 0.f;
            const int kstep = k >> 4;
            const int tile  = kstep * (N >> 5) + (n >> 5);
            const int lane  = (n & 31) | (((k >> 3) & 1) << 5);
            const int j     = k & 7;
            dst[off + tile * 512 + lane * 8 + j] = f2bf(v);
            return;
        }
        e -= sz; off += sz;
    }
}

// ---------------------------------------------------------------------------
// Feat prep: NCHW f32 -> NHWC bf16, plus xy = sqrt(d1^2+d2^2)
// ---------------------------------------------------------------------------
__global__ __launch_bounds__(256) void prep_feat(
    const float* __restrict__ depth, const float* __restrict__ feat,
    ushort* __restrict__ nhwc, float* __restrict__ xy)
{
    const int idx = blockIdx.x * 256 + threadIdx.x;
    const int b   = idx >> 17;
    const int yx  = idx & (HWSZ - 1);

    const float d1 = depth[(b * 3 + 1) * HWSZ + yx];
    const float d2 = depth[(b * 3 + 2) * HWSZ + yx];
    xy[idx] = sqrtf(d1 * d1 + d2 * d2);

    const float* fp = feat + (size_t)b * CC * HWSZ + yx;
    ushort* op = nhwc + (size_t)idx * CC;
    #pragma unroll
    for (int c = 0; c < CC; c += 8) {
        union { uint4 v; ushort u[8]; } t;
        #pragma unroll
        for (int j = 0; j < 8; ++j) t.u[j] = f2bf(fp[(size_t)(c + j) * HWSZ]);
        *(uint4*)(op + c) = t.v;
    }
}

// ---------------------------------------------------------------------------
// One dense layer, in place on A (bf16, swizzled LDS), 32x32x16 MFMA with
// SWAPPED operands: mfma(w_frag, act_frag). D: output col = (reg&3)+8*(reg>>2)
// +4*(lane>>5), act row = lane&31 -> packed uint2 writeback per 4 cols.
// Wave tiles (128-row block): N=256: 128r x 64c (RG=4,CT=2); N=128: 128r x 32c
// (RG=4); N=64: 64r x 32c (RG=2, 2Mx2N). Each B-frag load feeds RG MFMAs.
// Weights load directly global->VGPR from fragment-packed wt (L1/L2-hot).
// ---------------------------------------------------------------------------
template <int K, int N, bool RELU>
__device__ __forceinline__ void dense_layer(
    char* __restrict__ sA, const ushort* __restrict__ Wt,
    const float* __restrict__ Bg, int tid)
{
    constexpr int CT = (N == 256) ? 2 : 1;   // 32-col tiles per wave
    constexpr int RG = (N == 64) ? 2 : 4;    // 32-row groups per wave
    constexpr int KS = K / 16;               // 16-wide k steps

    const int lane = tid & 63, wv = tid >> 6;   // wv in 0..3
    const int row0 = (N == 64) ? (wv >> 1) * 64 : 0;
    const int col0 = (N == 64) ? (wv & 1) * 32 : wv * (N / 4);
    const int lrow = lane & 31;
    const int lkb  = (lane >> 5) * 16;   // byte offset of this lane's 8 bf16 in k

    f32x16 acc[RG][CT];
    #pragma unroll
    for (int rg = 0; rg < RG; ++rg)
        #pragma unroll
        for (int ct = 0; ct < CT; ++ct)
            #pragma unroll
            for (int t = 0; t < 16; ++t) acc[rg][ct][t] = 0.f;

    const char* wbase = (const char*)Wt + (size_t)lane * 16;

    for (int kst = 0; kst < KS; ++kst) {
        const int cb = kst * 32 + lkb;
        bf16x8 a[RG];
        #pragma unroll
        for (int rg = 0; rg < RG; ++rg)
            a[rg] = *(const bf16x8*)(sA + swA(row0 + rg * 32 + lrow, cb));
        #pragma unroll
        for (int ct = 0; ct < CT; ++ct) {
            const int tile = kst * (N >> 5) + (col0 >> 5) + ct;
            const bf16x8 bw = *(const bf16x8*)(wbase + tile * 1024);
            #pragma unroll
            for (int rg = 0; rg < RG; ++rg)
                acc[rg][ct] = __builtin_amdgcn_mfma_f32_32x32x16_bf16(bw, a[rg], acc[rg][ct], 0, 0, 0);
        }
    }
    __syncthreads();   // all waves done reading A -> safe in-place writeback

    // writeback: lane holds act row = row0+rg*32+(lane&31),
    // cols = col0 + ct*32 + 8q + 4*(lane>>5) + {0..3} from acc[rg][ct][4q..4q+3]
    #pragma unroll
    for (int ct = 0; ct < CT; ++ct) {
        #pragma unroll
        for (int q = 0; q < 4; ++q) {
            const int colb = col0 + ct * 32 + q * 8 + (lane >> 5) * 4;
            const float4 b4 = *(const float4*)(Bg + colb);
            #pragma unroll
            for (int rg = 0; rg < RG; ++rg) {
                float v0 = acc[rg][ct][q * 4 + 0] + b4.x;
                float v1 = acc[rg][ct][q * 4 + 1] + b4.y;
                float v2 = acc[rg][ct][q * 4 + 2] + b4.z;
                float v3 = acc[rg][ct][q * 4 + 3] + b4.w;
                if (RELU) {
                    v0 = fmaxf(v0, 0.f); v1 = fmaxf(v1, 0.f);
                    v2 = fmaxf(v2, 0.f); v3 = fmaxf(v3, 0.f);
                }
                uint2 pk;
                pk.x = cvtpk(v0, v1);
                pk.y = cvtpk(v2, v3);
                const int row = row0 + rg * 32 + lrow;
                *(uint2*)(sA + swA(row, colb * 2)) = pk;
            }
        }
    }
    __syncthreads();
}

// ---------------------------------------------------------------------------
// Fused: taps + PE MLP + gather-add + encoder MLP + softmax + output
// __launch_bounds__(256, 2): 256-reg unified budget (acc 128 + ~90 arch).
// 128 rows/block: setup/gather loop 2 items/thread; final = 2 threads/row.
// ---------------------------------------------------------------------------
template <bool USE_WS>
__global__ __launch_bounds__(256, 2) void fused_kernel(
    const float* __restrict__ depth, const float* __restrict__ feat,
    const float* __restrict__ coord,
    const float* __restrict__ pb0, const float* __restrict__ pb1,
    const float* __restrict__ pb2,
    const float* __restrict__ eb0, const float* __restrict__ eb1,
    const float* __restrict__ eb2,
    const float* __restrict__ ew3, const float* __restrict__ eb3,
    const ushort* __restrict__ wt,
    const ushort* __restrict__ nhwc, const float* __restrict__ xyws,
    float* __restrict__ out)
{
    extern __shared__ char lds[];
    char*  sA   = lds + OFF_A;
    int*   sTap = (int*)(lds + OFF_TAP);
    float* sPxy = (float*)(lds + OFF_PXY);
    float* sE3  = (float*)(lds + OFF_E3);

    const int tid  = threadIdx.x;
    const int row0g = blockIdx.x * ROWS;
    const int b     = row0g >> 17;   // QQ = 2^17, ROWS | QQ

    // stage final-layer weights (64x4 f32)
    sE3[tid] = ew3[tid];

    // taps + rel coords + pred_xy; fp32, contraction OFF (match numpy rounding)
    #pragma unroll
    for (int it = 0; it < 2; ++it) {
        #pragma clang fp contract(off)
        const int item = it * 256 + tid;
        const int r = item >> 2, s = item & 3;
        const int row = row0g + r;
        const float cy = coord[row * 2 + 0];
        const float cx = coord[row * 2 + 1];
        const float offy = (s < 2) ? -1.f : 1.f;
        const float offx = (s & 1) ? 1.f : -1.f;
        const float rx = 1.f / (float)HH, ry = 1.f / (float)WWID;
        float ccy = cy + (offy * rx + 1e-6f);
        float ccx = cx + (offx * ry + 1e-6f);
        ccy = fminf(fmaxf(ccy, -1.f + 1e-6f), 1.f - 1e-6f);
        ccx = fminf(fmaxf(ccx, -1.f + 1e-6f), 1.f - 1e-6f);
        int iy = (int)rintf(((ccy + 1.f) * (float)HH - 1.f) * 0.5f);
        int ix = (int)rintf(((ccx + 1.f) * (float)WWID - 1.f) * 0.5f);
        iy = min(max(iy, 0), HH - 1);
        ix = min(max(ix, 0), WWID - 1);
        const float qcy = -1.f + (2.f * (float)iy + 1.f) / (float)HH;
        const float qcx = -1.f + (2.f * (float)ix + 1.f) / (float)WWID;
        // rel coords -> A cols 2s, 2s+1 (bytes s*4..s*4+3; XOR only touches bits>=4)
        *(ushort*)(sA + swA(r, s * 4 + 0)) = f2bf((cy - qcy) * (float)HH);
        *(ushort*)(sA + swA(r, s * 4 + 2)) = f2bf((cx - qcx) * (float)WWID);
        // zero cols 8..15 (pe0 Kp=16; hi half-lanes read them)
        if (s == 0) {
            uint4 z; z.x = z.y = z.z = z.w = 0u;
            *(uint4*)(sA + swA(r, 16)) = z;
        }
        const int tap = iy * WWID + ix;
        sTap[r * 4 + s] = tap;
        float px;
        if (USE_WS) {
            px = xyws[b * HWSZ + tap];
        } else {
            const float d1 = depth[(b * 3 + 1) * HWSZ + tap];
            const float d2 = depth[(b * 3 + 2) * HWSZ + tap];
            px = sqrtf(d1 * d1 + d2 * d2);
        }
        sPxy[r * 4 + s] = px;
    }
    __syncthreads();

    // PE MLP (rel coords in A cols 0..7, zero-padded to 16)
    dense_layer<16,  64,  true >(sA, wt + WOFF_PE0, pb0, tid);
    dense_layer<64,  128, true >(sA, wt + WOFF_PE1, pb1, tid);
    dense_layer<128, 256, false>(sA, wt + WOFF_PE2, pb2, tid);

    // gather-add q_feat: A[r][s*64+c] += feat[b,c,tap]; item = (row, tap)
    #pragma unroll
    for (int it = 0; it < 2; ++it) {
        const int item = it * 256 + tid;
        const int gr = item >> 2, gs = item & 3;
        const int tap = sTap[gr * 4 + gs];
        const int cb0 = gs * 128;   // byte offset of this tap's 64 channels
        if (USE_WS) {
            const ushort* src = nhwc + ((size_t)b * HWSZ + tap) * CC;
            #pragma unroll
            for (int g = 0; g < 8; ++g) {
                char* dp = sA + swA(gr, cb0 + g * 16);
                union { uint4 v; ushort u[8]; } a, d;
                a.v = *(const uint4*)(src + g * 8);
                d.v = *(uint4*)dp;
                float s0 = bf2f(a.u[0]) + bf2f(d.u[0]);
                float s1 = bf2f(a.u[1]) + bf2f(d.u[1]);
                float s2 = bf2f(a.u[2]) + bf2f(d.u[2]);
                float s3 = bf2f(a.u[3]) + bf2f(d.u[3]);
                float s4 = bf2f(a.u[4]) + bf2f(d.u[4]);
                float s5 = bf2f(a.u[5]) + bf2f(d.u[5]);
                float s6 = bf2f(a.u[6]) + bf2f(d.u[6]);
                float s7 = bf2f(a.u[7]) + bf2f(d.u[7]);
                uint4 o;
                o.x = cvtpk(s0, s1); o.y = cvtpk(s2, s3);
                o.z = cvtpk(s4, s5); o.w = cvtpk(s6, s7);
                *(uint4*)dp = o;
            }
        } else {
            const float* fp = feat + (size_t)b * CC * HWSZ + tap;
            #pragma unroll 8
            for (int c = 0; c < CC; ++c) {
                ushort* p = (ushort*)(sA + swA(gr, cb0 + c * 2));
                *p = f2bf(bf2f(*p) + fp[(size_t)c * HWSZ]);
            }
        }
    }
    __syncthreads();

    // encoder MLP
    dense_layer<256, 256, true>(sA, wt + WOFF_E0, eb0, tid);
    dense_layer<256, 128, true>(sA, wt + WOFF_E1, eb1, tid);
    dense_layer<128, 64,  true>(sA, wt + WOFF_E2, eb2, tid);

    // final 64->4, softmax, weighted sum with pred_xy (2 threads per row).
    // Thread sub covers cols sub*32..sub*32+31 = four swizzled 16B LDS blocks.
    {
        const int fr = tid >> 1, sub = tid & 1;
        float l0 = 0.f, l1 = 0.f, l2 = 0.f, l3 = 0.f;
        #pragma unroll
        for (int g = 0; g < 4; ++g) {
            union { uint4 v; ushort u[8]; } h;
            h.v = *(const uint4*)(sA + swA(fr, sub * 64 + g * 16));
            #pragma unroll
            for (int kk = 0; kk < 8; ++kk) {
                const float a = bf2f(h.u[kk]);
                const float4 w = ((const float4*)sE3)[sub * 32 + g * 8 + kk];
                l0 = fmaf(a, w.x, l0);
                l1 = fmaf(a, w.y, l1);
                l2 = fmaf(a, w.z, l2);
                l3 = fmaf(a, w.w, l3);
            }
        }
        l0 += __shfl_xor(l0, 1);
        l1 += __shfl_xor(l1, 1);
        l2 += __shfl_xor(l2, 1);
        l3 += __shfl_xor(l3, 1);
        if (sub == 0) {
            l0 += eb3[0]; l1 += eb3[1]; l2 += eb3[2]; l3 += eb3[3];
            const float m  = fmaxf(fmaxf(l0, l1), fmaxf(l2, l3));
            const float e0 = expf(l0 - m), e1 = expf(l1 - m);
            const float e2 = expf(l2 - m), e3 = expf(l3 - m);
            const float inv = 1.f / (e0 + e1 + e2 + e3);
            const float o = (sPxy[fr * 4 + 0] * e0 + sPxy[fr * 4 + 1] * e1 +
                             sPxy[fr * 4 + 2] * e2 + sPxy[fr * 4 + 3] * e3) * inv;
            out[row0g + fr] = o;
        }
    }
}

// ---------------------------------------------------------------------------
extern "C" void kernel_launch(void* const* d_in, const int* in_sizes, int n_in,
                              void* d_out, int out_size, void* d_ws, size_t ws_size,
                              hipStream_t stream)
{
    const float* depth = (const float*)d_in[0];
    const float* feat  = (const float*)d_in[1];
    const float* coord = (const float*)d_in[2];
    const float* pw0 = (const float*)d_in[3],  *pb0 = (const float*)d_in[4];
    const float* pw1 = (const float*)d_in[5],  *pb1 = (const float*)d_in[6];
    const float* pw2 = (const float*)d_in[7],  *pb2 = (const float*)d_in[8];
    const float* ew0 = (const float*)d_in[9],  *eb0 = (const float*)d_in[10];
    const float* ew1 = (const float*)d_in[11], *eb1 = (const float*)d_in[12];
    const float* ew2 = (const float*)d_in[13], *eb2 = (const float*)d_in[14];
    const float* ew3 = (const float*)d_in[15], *eb3 = (const float*)d_in[16];
    float* out = (float*)d_out;

    const size_t nhwc_bytes = (size_t)NBATCH * HWSZ * CC * 2;
    const size_t xy_bytes   = (size_t)NBATCH * HWSZ * 4;
    const size_t wt_bytes   = (size_t)WTOTAL * 2;
    const bool use_ws = (ws_size >= nhwc_bytes + xy_bytes + wt_bytes);

    ushort* nhwc = (ushort*)d_ws;
    float*  xyws = (float*)((char*)d_ws + nhwc_bytes);
    ushort* wt   = use_ws ? (ushort*)((char*)d_ws + nhwc_bytes + xy_bytes)
                          : (ushort*)d_ws;

    WPack pack;
    pack.d[0] = { pw0, 8,   64,  4 };
    pack.d[1] = { pw1, 64,  128, 6 };
    pack.d[2] = { pw2, 128, 256, 7 };
    pack.d[3] = { ew0, 256, 256, 8 };
    pack.d[4] = { ew1, 256, 128, 8 };
    pack.d[5] = { ew2, 128, 64,  7 };
    prep_weights<<<WTOTAL / 256, 256, 0, stream>>>(pack, wt);

    const int nblocks = (NBATCH * QQ) / ROWS;   // 2048

    if (use_ws) {
        prep_feat<<<(NBATCH * HWSZ) / 256, 256, 0, stream>>>(depth, feat, nhwc, xyws);
        hipFuncSetAttribute((const void*)fused_kernel<true>,
                            hipFuncAttributeMaxDynamicSharedMemorySize, LDS_BYTES);
        fused_kernel<true><<<nblocks, THREADS, LDS_BYTES, stream>>>(
            depth, feat, coord, pb0, pb1, pb2, eb0, eb1, eb2, ew3, eb3,
            wt, nhwc, xyws, out);
    } else {
        hipFuncSetAttribute((const void*)fused_kernel<false>,
                            hipFuncAttributeMaxDynamicSharedMemorySize, LDS_BYTES);
        fused_kernel<false><<<nblocks, THREADS, LDS_BYTES, stream>>>(
            depth, feat, coord, pb0, pb1, pb2, eb0, eb1, eb2, ew3, eb3,
            wt, nhwc, xyws, out);
    }
}